// Round 3
// baseline (2982.027 us; speedup 1.0000x reference)
//
#include <hip/hip_runtime.h>
#include <hip/hip_bf16.h>

typedef __hip_bfloat16 bf;

#define NN 16384
#define EE 262144
#define ET (EE + NN)   // 278528

__device__ __forceinline__ float bf2f(bf x){ return __bfloat162float(x); }
__device__ __forceinline__ float ldf(const void* p, size_t i, int isbf){
  return isbf ? __bfloat162float(((const bf*)p)[i]) : ((const float*)p)[i];
}
__device__ __forceinline__ float gelu_f(float x){ return 0.5f*x*(1.0f+erff(x*0.7071067811865475f)); }
__device__ __forceinline__ void store_c(float* p, float v){ *p = v; }
__device__ __forceinline__ void store_c(bf* p, float v){ *p = __float2bfloat16(v); }

// ---------------- dtype detector ----------------
__global__ void k_detect(const void* nf, int* flag)
{
  int t = threadIdx.x;
  const float* f = (const float*)nf;
  int cnt = 0;
  for (int i = t; i < 4096; i += 256) {
    float a = fabsf(f[i]);
    if (a > 1e-5f && a < 100.0f) cnt++;   // NaN compares false
  }
  __shared__ int s[256];
  s[t] = cnt; __syncthreads();
  for (int st = 128; st > 0; st >>= 1) { if (t < st) s[t] += s[t+st]; __syncthreads(); }
  if (t == 0) *flag = (s[0] < 2048) ? 1 : 0;   // majority out-of-range => bf16
}

// ---------------- GEMM: C[M,N] = A[M,K] @ B[N,K]^T (+bias)(+gelu) ----------------
// a_fmt: 0 fp32 internal, 1 bf16 internal, 2 external. B/bias always external (elem offsets boff/bioff).
template<int ACT, typename TC>
__global__ __launch_bounds__(256)
void gemm_tn(const void* __restrict__ A, int a_fmt,
             const void* __restrict__ B, size_t boff,
             const void* __restrict__ bias, size_t bioff, int has_bias,
             TC* __restrict__ C, int M, int N, int K, const int* __restrict__ dflag)
{
  int isbf = *dflag;
  int af = (a_fmt == 2) ? isbf : a_fmt;
  const int BM=64, BN=64, BK=32;
  __shared__ float As[BK][BM+1];
  __shared__ float Bs[BK][BN+1];
  int bm = blockIdx.y * BM, bn = blockIdx.x * BN;
  int t = threadIdx.x;
  int tm = t >> 4, tn = t & 15;
  float acc[4][4] = {};
  for (int k0 = 0; k0 < K; k0 += BK) {
    for (int i = t; i < BM*BK; i += 256) {
      int ml = i >> 5, kl = i & 31;
      As[kl][ml] = ldf(A, (size_t)(bm+ml)*K + k0 + kl, af);
    }
    for (int i = t; i < BN*BK; i += 256) {
      int nl = i >> 5, kl = i & 31;
      Bs[kl][nl] = ldf(B, boff + (size_t)(bn+nl)*K + k0 + kl, isbf);
    }
    __syncthreads();
    #pragma unroll
    for (int kk = 0; kk < BK; ++kk) {
      float a[4], b[4];
      #pragma unroll
      for (int i=0;i<4;i++) a[i] = As[kk][tm*4+i];
      #pragma unroll
      for (int j=0;j<4;j++) b[j] = Bs[kk][tn*4+j];
      #pragma unroll
      for (int i=0;i<4;i++)
        #pragma unroll
        for (int j=0;j<4;j++) acc[i][j] += a[i]*b[j];
    }
    __syncthreads();
  }
  #pragma unroll
  for (int i=0;i<4;i++) {
    int m = bm + tm*4 + i;
    #pragma unroll
    for (int j=0;j<4;j++) {
      int n = bn + tn*4 + j;
      float v = acc[i][j];
      if (has_bias) v += ldf(bias, bioff + n, isbf);
      if (ACT==1) v = gelu_f(v);
      store_c(&C[(size_t)m*N + n], v);
    }
  }
}

// ---------------- CSR build ----------------
__global__ void k_count(const int* __restrict__ dst, int* __restrict__ deg)
{
  int e = blockIdx.x*256 + threadIdx.x;
  if (e >= ET) return;
  int d = (e < EE) ? dst[e] : (e - EE);
  atomicAdd(&deg[d], 1);
}

__global__ void k_scan(const int* __restrict__ deg, int* __restrict__ rowstart)
{
  __shared__ int csum[256];
  int t = threadIdx.x;
  int s = 0;
  for (int i=0;i<64;i++) s += deg[t*64+i];
  csum[t] = s;
  __syncthreads();
  if (t == 0) {
    int r = 0;
    for (int i=0;i<256;i++){ int v = csum[i]; csum[i] = r; r += v; }
    rowstart[NN] = r;
  }
  __syncthreads();
  int b = csum[t];
  for (int i=0;i<64;i++){ rowstart[t*64+i] = b; b += deg[t*64+i]; }
}

__global__ void k_scatter(const int* __restrict__ dst, const int* __restrict__ rowstart,
                          int* __restrict__ fill, int* __restrict__ csr)
{
  int e = blockIdx.x*256 + threadIdx.x;
  if (e >= ET) return;
  int d = (e < EE) ? dst[e] : (e - EE);
  int pos = rowstart[d] + atomicAdd(&fill[d], 1);
  csr[pos] = e;
}

__global__ void k_loopmean(const int* __restrict__ csr, const int* __restrict__ rowstart,
                           const void* __restrict__ edge_attr, bf* __restrict__ loopmean,
                           const int* __restrict__ dflag)
{
  int isbf = *dflag;
  int n = blockIdx.x, j = threadIdx.x;   // 64 threads
  int s = rowstart[n], e1 = rowstart[n+1];
  float sum = 0.f; int cnt = 0;
  for (int p = s; p < e1; ++p) {
    int eid = csr[p];
    if (eid < EE) { sum += ldf(edge_attr, (size_t)eid*64 + j, isbf); cnt++; }
  }
  loopmean[(size_t)n*64 + j] = __float2bfloat16(sum / (float)max(cnt, 1));
}

// Wc[l] = lin_edge_w[l] @ init_edge_w  -> [L,256,64] fp32
__global__ void k_wc(const void* __restrict__ We, const void* __restrict__ iew,
                     float* __restrict__ Wc, const int* __restrict__ dflag)
{
  int isbf = *dflag;
  int idx = blockIdx.x*256 + threadIdx.x;    // 32768
  int j = idx & 63, c = (idx >> 6) & 255, l = idx >> 14;
  float s = 0.f;
  for (int k=0;k<128;k++) s += ldf(We, ((size_t)l*256 + c)*128 + k, isbf) * ldf(iew, (size_t)k*64 + j, isbf);
  Wc[idx] = s;
}

// ---------------- per-edge logits ----------------
__global__ __launch_bounds__(256)
void k_logits(const float* __restrict__ Wc, const bf* __restrict__ xl, const bf* __restrict__ xr,
              const int* __restrict__ src, const int* __restrict__ dst,
              const void* __restrict__ edge_attr, const bf* __restrict__ loopmean,
              const void* __restrict__ att, size_t att_off, float* __restrict__ logits,
              const int* __restrict__ dflag)
{
  int isbf = *dflag;
  int t = threadIdx.x;                       // channel (head = t>>5)
  float w[64];
  #pragma unroll
  for (int k=0;k<64;k++) w[k] = Wc[t*64 + k];
  float attv = ldf(att, att_off + t, isbf);
  __shared__ float sattr[64];
  __shared__ float rs[256];
  for (int e = blockIdx.x; e < ET; e += gridDim.x) {
    int s_, d_; bool orig = (e < EE);
    if (orig) { s_ = src[e]; d_ = dst[e]; } else { s_ = d_ = e - EE; }
    __syncthreads();
    if (t < 64) sattr[t] = orig ? ldf(edge_attr, (size_t)e*64 + t, isbf)
                                : bf2f(loopmean[(size_t)(e-EE)*64 + t]);
    __syncthreads();
    float acc = 0.f;
    #pragma unroll
    for (int k=0;k<64;k++) acc += w[k] * sattr[k];
    float m = acc + bf2f(xl[(size_t)s_*256 + t]) + bf2f(xr[(size_t)d_*256 + t]);
    float g = (m >= 0.f) ? m : 0.2f*m;
    rs[t] = attv * g;
    __syncthreads();
    for (int st = 16; st > 0; st >>= 1) { if ((t&31) < st) rs[t] += rs[t+st]; __syncthreads(); }
    if ((t & 31) == 0) logits[(size_t)e*8 + (t>>5)] = rs[t];
  }
}

// ---------------- per-node: softmax + aggregate + bias + residual + LN1 -> hbuf ----------------
__global__ __launch_bounds__(256)
void k_nodeagg(const int* __restrict__ csr, const int* __restrict__ rowstart, const int* __restrict__ src,
               const float* __restrict__ logits, const bf* __restrict__ xl, const float* __restrict__ xbuf,
               const void* __restrict__ gat_bias, const void* __restrict__ ln1g, const void* __restrict__ ln1b,
               size_t poff, float* __restrict__ hbuf, const int* __restrict__ dflag)
{
  int isbf = *dflag;
  int n = blockIdx.x, t = threadIdx.x;
  int s = rowstart[n], deg = rowstart[n+1] - s;
  int h = t >> 5;
  __shared__ float mh[8], sh[8];
  __shared__ float r[256];

  if (t < 8) {
    float m = -3.4e38f;
    for (int j = 0; j < deg; ++j) m = fmaxf(m, logits[(size_t)csr[s+j]*8 + t]);
    float sum = 0.f;
    for (int j = 0; j < deg; ++j) sum += expf(logits[(size_t)csr[s+j]*8 + t] - m);
    mh[t] = m; sh[t] = sum;
  }
  __syncthreads();
  float m = mh[h], sd = sh[h];

  float acc = 0.f;
  for (int j = 0; j < deg; ++j) {
    int eid = csr[s+j];
    int sn = (eid < EE) ? src[eid] : (eid - EE);
    float al = expf(logits[(size_t)eid*8 + h] - m);
    acc += al * bf2f(xl[(size_t)sn*256 + t]);
  }
  float outv = acc / (sd + 1e-16f) + ldf(gat_bias, poff + t, isbf) + xbuf[(size_t)n*256 + t];

  r[t] = outv; __syncthreads();
  for (int st = 128; st > 0; st >>= 1) { if (t < st) r[t] += r[t+st]; __syncthreads(); }
  float mu = r[0] * (1.f/256.f);
  __syncthreads();
  float d = outv - mu;
  r[t] = d*d; __syncthreads();
  for (int st = 128; st > 0; st >>= 1) { if (t < st) r[t] += r[t+st]; __syncthreads(); }
  float var = r[0] * (1.f/256.f);
  hbuf[(size_t)n*256 + t] = d * rsqrtf(var + 1e-5f) * ldf(ln1g, poff + t, isbf) + ldf(ln1b, poff + t, isbf);
}

// ---------------- residual + LN2 -> xbuf ----------------
__global__ __launch_bounds__(256)
void k_ln_add(const float* __restrict__ a, const bf* __restrict__ b2,
              const void* __restrict__ gg, const void* __restrict__ bb, size_t poff,
              float* __restrict__ out, const int* __restrict__ dflag)
{
  int isbf = *dflag;
  int n = blockIdx.x, t = threadIdx.x;
  __shared__ float r[256];
  float x = a[(size_t)n*256 + t] + bf2f(b2[(size_t)n*256 + t]);
  r[t] = x; __syncthreads();
  for (int st = 128; st > 0; st >>= 1) { if (t < st) r[t] += r[t+st]; __syncthreads(); }
  float mu = r[0] * (1.f/256.f);
  __syncthreads();
  float d = x - mu;
  r[t] = d*d; __syncthreads();
  for (int st = 128; st > 0; st >>= 1) { if (t < st) r[t] += r[t+st]; __syncthreads(); }
  float var = r[0] * (1.f/256.f);
  out[(size_t)n*256 + t] = d * rsqrtf(var + 1e-5f) * ldf(gg, poff + t, isbf) + ldf(bb, poff + t, isbf);
}

__global__ void k_out(const float* __restrict__ x, void* __restrict__ out, const int* __restrict__ dflag)
{
  int isbf = *dflag;
  int i = blockIdx.x*256 + threadIdx.x;
  if (isbf) ((bf*)out)[i] = __float2bfloat16(x[i]);
  else      ((float*)out)[i] = x[i];
}

extern "C" void kernel_launch(void* const* d_in, const int* in_sizes, int n_in,
                              void* d_out, int out_size, void* d_ws, size_t ws_size,
                              hipStream_t stream)
{
  const void* node_feats = d_in[0];
  const int*  edge_index = (const int*)d_in[1];
  const void* edge_attr  = d_in[2];
  const void* init_node_w= d_in[3];
  const void* init_edge_w= d_in[4];
  const void* lin_l_w    = d_in[5];
  const void* lin_l_b    = d_in[6];
  const void* lin_r_w    = d_in[7];
  const void* lin_r_b    = d_in[8];
  const void* lin_edge_w = d_in[9];
  const void* att        = d_in[10];
  const void* gat_bias   = d_in[11];
  const void* ln1_g      = d_in[12];
  const void* ln1_b      = d_in[13];
  const void* mlp_w1     = d_in[14];
  const void* mlp_w2     = d_in[15];
  const void* ln2_g      = d_in[16];
  const void* ln2_b      = d_in[17];

  const int* srcp = edge_index;
  const int* dstp = edge_index + EE;

  char* p = (char*)d_ws;
  auto alloc = [&](size_t bytes) { void* r = (void*)p; p += (bytes + 255) & ~(size_t)255; return r; };
  int*   dflag   = (int*)alloc(256);
  int*   deg     = (int*)alloc((size_t)NN*4);
  int*   rowstart= (int*)alloc((size_t)(NN+1)*4);
  int*   fill    = (int*)alloc((size_t)NN*4);
  int*   csr     = (int*)alloc((size_t)ET*4);
  float* Wc2     = (float*)alloc((size_t)2*256*64*4);
  bf*    loopmean= (bf*)alloc((size_t)NN*64*2);
  float* logits  = (float*)alloc((size_t)ET*8*4);
  float* xbuf    = (float*)alloc((size_t)NN*256*4);
  float* hbuf    = (float*)alloc((size_t)NN*256*4);
  bf*    xl      = (bf*)alloc((size_t)NN*256*2);
  bf*    xr      = (bf*)alloc((size_t)NN*256*2);
  bf*    ymid    = xl;              // [NN,512] bf16 aliases xl+xr (dead at MLP time)
  bf*    y2      = (bf*)d_out;      // bf16 scratch; final k_out overwrites

  hipMemsetAsync(deg,  0, (size_t)NN*4, stream);
  hipMemsetAsync(fill, 0, (size_t)NN*4, stream);

  k_detect <<<1, 256, 0, stream>>>(node_feats, dflag);

  k_count  <<<(ET+255)/256, 256, 0, stream>>>(dstp, deg);
  k_scan   <<<1, 256, 0, stream>>>(deg, rowstart);
  k_scatter<<<(ET+255)/256, 256, 0, stream>>>(dstp, rowstart, fill, csr);
  k_loopmean<<<NN, 64, 0, stream>>>(csr, rowstart, edge_attr, loopmean, dflag);
  k_wc     <<<128, 256, 0, stream>>>(lin_edge_w, init_edge_w, Wc2, dflag);

  gemm_tn<0, float><<<dim3(4, 256), 256, 0, stream>>>(node_feats, 2, init_node_w, 0, nullptr, 0, 0,
                                                      xbuf, NN, 256, 768, dflag);

  for (int l = 0; l < 2; ++l) {
    size_t wo  = (size_t)l*256*256;   // lin_l_w / lin_r_w slice (elements)
    size_t bo  = (size_t)l*256;       // 256-vector params
    gemm_tn<0, bf><<<dim3(4, 256), 256, 0, stream>>>(xbuf, 0, lin_l_w, wo, lin_l_b, bo, 1,
                                                     xl, NN, 256, 256, dflag);
    gemm_tn<0, bf><<<dim3(4, 256), 256, 0, stream>>>(xbuf, 0, lin_r_w, wo, lin_r_b, bo, 1,
                                                     xr, NN, 256, 256, dflag);
    k_logits<<<4096, 256, 0, stream>>>(Wc2 + (size_t)l*256*64, xl, xr, srcp, dstp,
                                       edge_attr, loopmean, att, (size_t)l*256, logits, dflag);
    k_nodeagg<<<NN, 256, 0, stream>>>(csr, rowstart, srcp, logits, xl, xbuf,
                                      gat_bias, ln1_g, ln1_b, bo, hbuf, dflag);
    gemm_tn<1, bf><<<dim3(8, 256), 256, 0, stream>>>(hbuf, 0, mlp_w1, (size_t)l*512*256, nullptr, 0, 0,
                                                     ymid, NN, 512, 256, dflag);
    gemm_tn<0, bf><<<dim3(4, 256), 256, 0, stream>>>(ymid, 1, mlp_w2, (size_t)l*256*512, nullptr, 0, 0,
                                                     y2, NN, 256, 512, dflag);
    k_ln_add<<<NN, 256, 0, stream>>>(hbuf, y2, ln2_g, ln2_b, bo, xbuf, dflag);
  }

  k_out<<<(NN*256)/256, 256, 0, stream>>>(xbuf, d_out, dflag);
}

// Round 4
// 1089.219 us; speedup vs baseline: 2.7378x; 2.7378x over previous
//
#include <hip/hip_runtime.h>

typedef unsigned short u16;
typedef __attribute__((ext_vector_type(8))) short s8v;   // 8 bf16 (4 VGPRs) — MFMA A/B frag
typedef __attribute__((ext_vector_type(4))) float f4v;   // 4 fp32 — MFMA C/D frag

#define NN 16384
#define EE 262144
#define ET (EE + NN)   // 278528 = 4352 * 64

__device__ __forceinline__ float bfu(u16 h){ return __uint_as_float((unsigned)h << 16); }
__device__ __forceinline__ u16 f2bf(float f){
  unsigned u = __float_as_uint(f);
  unsigned r = u + 0x7FFFu + ((u >> 16) & 1u);   // RNE
  return (u16)(r >> 16);
}
__device__ __forceinline__ float ldf(const void* p, size_t i, int isbf){
  return isbf ? bfu(((const u16*)p)[i]) : ((const float*)p)[i];
}
__device__ __forceinline__ float gelu_f(float x){ return 0.5f*x*(1.0f+erff(x*0.7071067811865475f)); }

// load 8 consecutive elements as packed bf16 (uint4)
__device__ __forceinline__ uint4 load8bf(const void* p, size_t eoff, int isbf){
  if (isbf) return *(const uint4*)((const u16*)p + eoff);
  const float* f = (const float*)p + eoff;
  uint4 r;
  r.x = (unsigned)f2bf(f[0]) | ((unsigned)f2bf(f[1])<<16);
  r.y = (unsigned)f2bf(f[2]) | ((unsigned)f2bf(f[3])<<16);
  r.z = (unsigned)f2bf(f[4]) | ((unsigned)f2bf(f[5])<<16);
  r.w = (unsigned)f2bf(f[6]) | ((unsigned)f2bf(f[7])<<16);
  return r;
}

// ---------------- dtype detector ----------------
__global__ void k_detect(const void* nf, int* flag)
{
  int t = threadIdx.x;
  const float* f = (const float*)nf;
  int cnt = 0;
  for (int i = t; i < 4096; i += 256) {
    float a = fabsf(f[i]);
    if (a > 1e-5f && a < 100.0f) cnt++;   // NaN compares false
  }
  __shared__ int s[256];
  s[t] = cnt; __syncthreads();
  for (int st = 128; st > 0; st >>= 1) { if (t < st) s[t] += s[t+st]; __syncthreads(); }
  if (t == 0) *flag = (s[0] < 2048) ? 1 : 0;   // majority out-of-range => bf16
}

// ---------------- MFMA GEMM: C[M,N] = A[M,K] @ B[N,K]^T (+bias)(+gelu) ----------------
// a_fmt: 0 fp32 internal, 1 bf16(u16) internal, 2 external (detected). B/bias external.
// BM=BN=128, BK=32. 4 waves, each 64x64 (4x4 MFMA 16x16x32 tiles). LDS row stride 40 (2-way bank alias = free).
template<int ACT, int CFMT>
__global__ __launch_bounds__(256)
void mfma_gemm(const void* __restrict__ A, int a_fmt,
               const void* __restrict__ B, size_t boff,
               const void* __restrict__ bias, size_t bioff, int has_bias,
               void* __restrict__ C, int M, int N, int K,
               const int* __restrict__ dflag)
{
  int isbf = *dflag;
  int af = (a_fmt == 2) ? isbf : a_fmt;
  __shared__ u16 As[128*40];
  __shared__ u16 Bs[128*40];
  int bm = blockIdx.y*128, bn = blockIdx.x*128;
  int t = threadIdx.x;
  int w = t>>6, lane = t&63, l4 = lane&15, quad = lane>>4;
  int wm = w>>1, wn = w&1;
  f4v zero = {0.f,0.f,0.f,0.f};
  f4v acc[4][4];
  #pragma unroll
  for (int i=0;i<4;i++)
    #pragma unroll
    for (int j=0;j<4;j++) acc[i][j] = zero;

  for (int k0 = 0; k0 < K; k0 += 32) {
    __syncthreads();
    #pragma unroll
    for (int it = 0; it < 2; ++it) {
      int sid = t + it*256;
      int row = sid >> 2, sk = sid & 3;
      uint4 va = load8bf(A, (size_t)(bm+row)*K + k0 + sk*8, af);
      *(uint4*)&As[row*40 + sk*8] = va;
      uint4 vb = load8bf(B, boff + (size_t)(bn+row)*K + k0 + sk*8, isbf);
      *(uint4*)&Bs[row*40 + sk*8] = vb;
    }
    __syncthreads();
    s8v a[4], b[4];
    #pragma unroll
    for (int i=0;i<4;i++) a[i] = *(const s8v*)&As[(wm*64 + i*16 + l4)*40 + quad*8];
    #pragma unroll
    for (int j=0;j<4;j++) b[j] = *(const s8v*)&Bs[(wn*64 + j*16 + l4)*40 + quad*8];
    #pragma unroll
    for (int i=0;i<4;i++)
      #pragma unroll
      for (int j=0;j<4;j++)
        acc[i][j] = __builtin_amdgcn_mfma_f32_16x16x32_bf16(a[i], b[j], acc[i][j], 0,0,0);
  }
  #pragma unroll
  for (int i=0;i<4;i++)
    #pragma unroll
    for (int j=0;j<4;j++) {
      int col = bn + wn*64 + j*16 + l4;
      float bv = has_bias ? ldf(bias, bioff + col, isbf) : 0.f;
      #pragma unroll
      for (int r=0;r<4;r++) {
        int row = bm + wm*64 + i*16 + quad*4 + r;
        float v = acc[i][j][r] + bv;
        if (ACT==1) v = gelu_f(v);
        if (CFMT==1) ((u16*)C)[(size_t)row*N + col] = f2bf(v);
        else         ((float*)C)[(size_t)row*N + col] = v;
      }
    }
}

// ---------------- CSR build ----------------
__global__ void k_count(const int* __restrict__ dst, int* __restrict__ deg)
{
  int e = blockIdx.x*256 + threadIdx.x;
  if (e >= ET) return;
  int d = (e < EE) ? dst[e] : (e - EE);
  atomicAdd(&deg[d], 1);
}

__global__ void k_scan(const int* __restrict__ deg, int* __restrict__ rowstart)
{
  __shared__ int csum[256];
  int t = threadIdx.x;
  int s = 0;
  for (int i=0;i<64;i++) s += deg[t*64+i];
  csum[t] = s;
  __syncthreads();
  if (t == 0) {
    int r = 0;
    for (int i=0;i<256;i++){ int v = csum[i]; csum[i] = r; r += v; }
    rowstart[NN] = r;
  }
  __syncthreads();
  int b = csum[t];
  for (int i=0;i<64;i++){ rowstart[t*64+i] = b; b += deg[t*64+i]; }
}

__global__ void k_scatter(const int* __restrict__ dst, const int* __restrict__ rowstart,
                          int* __restrict__ fill, int* __restrict__ csr)
{
  int e = blockIdx.x*256 + threadIdx.x;
  if (e >= ET) return;
  int d = (e < EE) ? dst[e] : (e - EE);
  int pos = rowstart[d] + atomicAdd(&fill[d], 1);
  csr[pos] = e;
}

__global__ void k_loopmean(const int* __restrict__ csr, const int* __restrict__ rowstart,
                           const void* __restrict__ edge_attr, u16* __restrict__ loopmean,
                           const int* __restrict__ dflag)
{
  int isbf = *dflag;
  int n = blockIdx.x, j = threadIdx.x;   // 64 threads
  int s = rowstart[n], e1 = rowstart[n+1];
  float sum = 0.f; int cnt = 0;
  for (int p = s; p < e1; ++p) {
    int eid = csr[p];
    if (eid < EE) { sum += ldf(edge_attr, (size_t)eid*64 + j, isbf); cnt++; }
  }
  loopmean[(size_t)n*64 + j] = f2bf(sum / (float)max(cnt, 1));
}

// Wc[l] = lin_edge_w[l] ([256,128]) @ init_edge_w ([128,64]) -> [L,256,64] bf16
__global__ void k_wc(const void* __restrict__ We, const void* __restrict__ iew,
                     u16* __restrict__ Wcb, const int* __restrict__ dflag)
{
  int isbf = *dflag;
  int idx = blockIdx.x*256 + threadIdx.x;    // 32768
  int j = idx & 63, c = (idx >> 6) & 255, l = idx >> 14;
  float s = 0.f;
  for (int k=0;k<128;k++) s += ldf(We, ((size_t)l*256 + c)*128 + k, isbf) * ldf(iew, (size_t)k*64 + j, isbf);
  Wcb[idx] = f2bf(s);
}

// ---------------- fused MFMA edge logits ----------------
// Per 64-edge tile: geattr = attr_tile[64,64] @ Wc^T[64,256] (MFMA, Wc in LDS),
// epilogue: + xl[src] + xr[dst], leaky, * att, shfl-reduce 32ch/head -> logits[e][h].
__global__ __launch_bounds__(256)
void k_logits_mfma(const u16* __restrict__ Wcb, const u16* __restrict__ xl, const u16* __restrict__ xr,
                   const int* __restrict__ src, const int* __restrict__ dst,
                   const void* __restrict__ edge_attr, const u16* __restrict__ loopmean,
                   const void* __restrict__ att, size_t att_off, float* __restrict__ logits,
                   const int* __restrict__ dflag)
{
  int isbf = *dflag;
  __shared__ u16 Bs[256*72];   // Wc, row stride 72 (2-way bank alias)
  __shared__ u16 As[64*72];    // attr tile
  int t = threadIdx.x;
  int w = t>>6, lane = t&63, l4 = lane&15, quad = lane>>4;

  // stage Wc once per block
  #pragma unroll
  for (int it = 0; it < 8; ++it) {
    int sid = t + it*256;
    int row = sid >> 3, sk = sid & 7;
    *(uint4*)&Bs[row*72 + sk*8] = *(const uint4*)&Wcb[row*64 + sk*8];
  }
  float attv[16];
  #pragma unroll
  for (int j=0;j<16;++j) attv[j] = ldf(att, att_off + j*16 + l4, isbf);

  f4v zero = {0.f,0.f,0.f,0.f};
  for (int tile = blockIdx.x; tile < ET/64; tile += gridDim.x) {
    int e0 = tile*64;
    __syncthreads();
    #pragma unroll
    for (int it=0; it<2; ++it){
      int sid = t + it*256;
      int row = sid>>3, sk = sid&7;
      int e = e0 + row;
      uint4 v;
      if (e < EE) v = load8bf(edge_attr, (size_t)e*64 + sk*8, isbf);
      else        v = *(const uint4*)&loopmean[(size_t)(e-EE)*64 + sk*8];
      *(uint4*)&As[row*72 + sk*8] = v;
    }
    __syncthreads();
    f4v acc[16];
    #pragma unroll
    for (int j=0;j<16;++j) acc[j] = zero;
    #pragma unroll
    for (int ks=0; ks<2; ++ks){
      s8v a = *(const s8v*)&As[(w*16 + l4)*72 + ks*32 + quad*8];
      #pragma unroll
      for (int j=0;j<16;++j){
        s8v b = *(const s8v*)&Bs[(j*16 + l4)*72 + ks*32 + quad*8];
        acc[j] = __builtin_amdgcn_mfma_f32_16x16x32_bf16(a, b, acc[j], 0,0,0);
      }
    }
    // epilogue: rows of this wave's 16-edge tile are quad*4+r
    int sidx[4], didx[4];
    #pragma unroll
    for (int r=0;r<4;++r){
      int e = e0 + w*16 + quad*4 + r;
      bool orig = (e < EE);
      sidx[r] = orig ? src[e] : (e-EE);
      didx[r] = orig ? dst[e] : (e-EE);
    }
    #pragma unroll
    for (int j=0;j<16;++j){
      int c = j*16 + l4;
      #pragma unroll
      for (int r=0;r<4;++r){
        float m = acc[j][r] + bfu(xl[(size_t)sidx[r]*256 + c]) + bfu(xr[(size_t)didx[r]*256 + c]);
        float g = (m >= 0.f) ? m : 0.2f*m;
        float v = attv[j]*g;
        v += __shfl_xor(v,1); v += __shfl_xor(v,2); v += __shfl_xor(v,4); v += __shfl_xor(v,8);
        acc[j][r] = v;   // all 16 lanes of the group now hold the channel-group sum
      }
    }
    if (l4 == 0){
      #pragma unroll
      for (int h=0;h<8;++h)
        #pragma unroll
        for (int r=0;r<4;++r){
          int e = e0 + w*16 + quad*4 + r;
          logits[(size_t)e*8 + h] = acc[2*h][r] + acc[2*h+1][r];
        }
    }
  }
}

// ---------------- per-node: softmax + aggregate + bias + residual + LN1 -> hbuf ----------------
__global__ __launch_bounds__(256)
void k_nodeagg(const int* __restrict__ csr, const int* __restrict__ rowstart, const int* __restrict__ src,
               const float* __restrict__ logits, const u16* __restrict__ xl, const float* __restrict__ xbuf,
               const void* __restrict__ gat_bias, const void* __restrict__ ln1g, const void* __restrict__ ln1b,
               size_t poff, float* __restrict__ hbuf, const int* __restrict__ dflag)
{
  int isbf = *dflag;
  int n = blockIdx.x, t = threadIdx.x;
  int s = rowstart[n], deg = rowstart[n+1] - s;
  int h = t >> 5;
  __shared__ float st[8][9];
  __shared__ float mh[8], sh[8];
  __shared__ float r[256];

  // per-head max, 64 threads (8 heads x 8 slots)
  if (t < 64) {
    int hh = t & 7, sl = t >> 3;
    float m = -3.4e38f;
    for (int j = sl; j < deg; j += 8) m = fmaxf(m, logits[(size_t)csr[s+j]*8 + hh]);
    st[sl][hh] = m;
  }
  __syncthreads();
  if (t < 8) { float m = st[0][t]; for (int q=1;q<8;q++) m = fmaxf(m, st[q][t]); mh[t] = m; }
  __syncthreads();
  if (t < 64) {
    int hh = t & 7, sl = t >> 3;
    float m = mh[hh], sum = 0.f;
    for (int j = sl; j < deg; j += 8) sum += expf(logits[(size_t)csr[s+j]*8 + hh] - m);
    st[sl][hh] = sum;
  }
  __syncthreads();
  if (t < 8) { float sm = 0.f; for (int q=0;q<8;q++) sm += st[q][t]; sh[t] = sm; }
  __syncthreads();
  float m = mh[h], sd = sh[h];

  float acc = 0.f;
  for (int j = 0; j < deg; ++j) {
    int eid = csr[s+j];
    int sn = (eid < EE) ? src[eid] : (eid - EE);
    float al = expf(logits[(size_t)eid*8 + h] - m);
    acc += al * bfu(xl[(size_t)sn*256 + t]);
  }
  float outv = acc / (sd + 1e-16f) + ldf(gat_bias, poff + t, isbf) + xbuf[(size_t)n*256 + t];

  r[t] = outv; __syncthreads();
  for (int st2 = 128; st2 > 0; st2 >>= 1) { if (t < st2) r[t] += r[t+st2]; __syncthreads(); }
  float mu = r[0] * (1.f/256.f);
  __syncthreads();
  float d = outv - mu;
  r[t] = d*d; __syncthreads();
  for (int st2 = 128; st2 > 0; st2 >>= 1) { if (t < st2) r[t] += r[t+st2]; __syncthreads(); }
  float var = r[0] * (1.f/256.f);
  hbuf[(size_t)n*256 + t] = d * rsqrtf(var + 1e-5f) * ldf(ln1g, poff + t, isbf) + ldf(ln1b, poff + t, isbf);
}

// ---------------- residual + LN2 -> xbuf ----------------
__global__ __launch_bounds__(256)
void k_ln_add(const float* __restrict__ a, const u16* __restrict__ b2,
              const void* __restrict__ gg, const void* __restrict__ bb, size_t poff,
              float* __restrict__ out, const int* __restrict__ dflag)
{
  int isbf = *dflag;
  int n = blockIdx.x, t = threadIdx.x;
  __shared__ float r[256];
  float x = a[(size_t)n*256 + t] + bfu(b2[(size_t)n*256 + t]);
  r[t] = x; __syncthreads();
  for (int st = 128; st > 0; st >>= 1) { if (t < st) r[t] += r[t+st]; __syncthreads(); }
  float mu = r[0] * (1.f/256.f);
  __syncthreads();
  float d = x - mu;
  r[t] = d*d; __syncthreads();
  for (int st = 128; st > 0; st >>= 1) { if (t < st) r[t] += r[t+st]; __syncthreads(); }
  float var = r[0] * (1.f/256.f);
  out[(size_t)n*256 + t] = d * rsqrtf(var + 1e-5f) * ldf(gg, poff + t, isbf) + ldf(bb, poff + t, isbf);
}

__global__ void k_out(const float* __restrict__ x, void* __restrict__ out, const int* __restrict__ dflag)
{
  int isbf = *dflag;
  int i = blockIdx.x*256 + threadIdx.x;
  if (isbf) ((u16*)out)[i] = f2bf(x[i]);
  else      ((float*)out)[i] = x[i];
}

extern "C" void kernel_launch(void* const* d_in, const int* in_sizes, int n_in,
                              void* d_out, int out_size, void* d_ws, size_t ws_size,
                              hipStream_t stream)
{
  const void* node_feats = d_in[0];
  const int*  edge_index = (const int*)d_in[1];
  const void* edge_attr  = d_in[2];
  const void* init_node_w= d_in[3];
  const void* init_edge_w= d_in[4];
  const void* lin_l_w    = d_in[5];
  const void* lin_l_b    = d_in[6];
  const void* lin_r_w    = d_in[7];
  const void* lin_r_b    = d_in[8];
  const void* lin_edge_w = d_in[9];
  const void* att        = d_in[10];
  const void* gat_bias   = d_in[11];
  const void* ln1_g      = d_in[12];
  const void* ln1_b      = d_in[13];
  const void* mlp_w1     = d_in[14];
  const void* mlp_w2     = d_in[15];
  const void* ln2_g      = d_in[16];
  const void* ln2_b      = d_in[17];

  const int* srcp = edge_index;
  const int* dstp = edge_index + EE;

  char* p = (char*)d_ws;
  auto alloc = [&](size_t bytes) { void* r = (void*)p; p += (bytes + 255) & ~(size_t)255; return r; };
  int*   dflag   = (int*)alloc(256);
  int*   deg     = (int*)alloc((size_t)NN*4);
  int*   rowstart= (int*)alloc((size_t)(NN+1)*4);
  int*   fill    = (int*)alloc((size_t)NN*4);
  int*   csr     = (int*)alloc((size_t)ET*4);
  u16*   Wcb     = (u16*)alloc((size_t)2*256*64*2);
  u16*   loopmean= (u16*)alloc((size_t)NN*64*2);
  float* logits  = (float*)alloc((size_t)ET*8*4);
  float* xbuf    = (float*)alloc((size_t)NN*256*4);
  float* hbuf    = (float*)alloc((size_t)NN*256*4);
  u16*   xl      = (u16*)alloc((size_t)NN*256*2);
  u16*   xr      = (u16*)alloc((size_t)NN*256*2);
  u16*   ymid    = xl;              // [NN,512] bf16 aliases xl+xr (dead at MLP time)
  u16*   y2      = (u16*)d_out;     // bf16 scratch; final k_out overwrites

  hipMemsetAsync(deg,  0, (size_t)NN*4, stream);
  hipMemsetAsync(fill, 0, (size_t)NN*4, stream);

  k_detect <<<1, 256, 0, stream>>>(node_feats, dflag);

  k_count  <<<(ET+255)/256, 256, 0, stream>>>(dstp, deg);
  k_scan   <<<1, 256, 0, stream>>>(deg, rowstart);
  k_scatter<<<(ET+255)/256, 256, 0, stream>>>(dstp, rowstart, fill, csr);
  k_loopmean<<<NN, 64, 0, stream>>>(csr, rowstart, edge_attr, loopmean, dflag);
  k_wc     <<<128, 256, 0, stream>>>(lin_edge_w, init_edge_w, Wcb, dflag);

  // x = node_feats @ init_node_w.T  (fp32 out)
  mfma_gemm<0,0><<<dim3(2,128), 256, 0, stream>>>(node_feats, 2, init_node_w, 0, nullptr, 0, 0,
                                                  xbuf, NN, 256, 768, dflag);

  for (int l = 0; l < 2; ++l) {
    size_t wo = (size_t)l*256*256;
    size_t bo = (size_t)l*256;
    mfma_gemm<0,1><<<dim3(2,128), 256, 0, stream>>>(xbuf, 0, lin_l_w, wo, lin_l_b, bo, 1,
                                                    xl, NN, 256, 256, dflag);
    mfma_gemm<0,1><<<dim3(2,128), 256, 0, stream>>>(xbuf, 0, lin_r_w, wo, lin_r_b, bo, 1,
                                                    xr, NN, 256, 256, dflag);
    k_logits_mfma<<<2176, 256, 0, stream>>>(Wcb + (size_t)l*256*64, xl, xr, srcp, dstp,
                                            edge_attr, loopmean, att, (size_t)l*256, logits, dflag);
    k_nodeagg<<<NN, 256, 0, stream>>>(csr, rowstart, srcp, logits, xl, xbuf,
                                      gat_bias, ln1_g, ln1_b, bo, hbuf, dflag);
    mfma_gemm<1,1><<<dim3(4,128), 256, 0, stream>>>(hbuf, 0, mlp_w1, (size_t)l*512*256, nullptr, 0, 0,
                                                    ymid, NN, 512, 256, dflag);
    mfma_gemm<0,1><<<dim3(2,128), 256, 0, stream>>>(ymid, 1, mlp_w2, (size_t)l*256*512, nullptr, 0, 0,
                                                    y2, NN, 256, 512, dflag);
    k_ln_add<<<NN, 256, 0, stream>>>(hbuf, y2, ln2_g, ln2_b, bo, xbuf, dflag);
  }

  k_out<<<(NN*256)/256, 256, 0, stream>>>(xbuf, d_out, dflag);
}

// Round 5
// 892.053 us; speedup vs baseline: 3.3429x; 1.2210x over previous
//
#include <hip/hip_runtime.h>

typedef unsigned short u16;
typedef __attribute__((ext_vector_type(8))) short s8v;   // 8 bf16 (4 VGPRs) — MFMA A/B frag
typedef __attribute__((ext_vector_type(4))) float f4v;   // 4 fp32 — MFMA C/D frag

#define NN 16384
#define EE 262144
#define ET (EE + NN)   // 278528

__device__ __forceinline__ float bfu(u16 h){ return __uint_as_float((unsigned)h << 16); }
__device__ __forceinline__ u16 f2bf(float f){
  unsigned u = __float_as_uint(f);
  unsigned r = u + 0x7FFFu + ((u >> 16) & 1u);   // RNE
  return (u16)(r >> 16);
}
__device__ __forceinline__ float ldf(const void* p, size_t i, int isbf){
  return isbf ? bfu(((const u16*)p)[i]) : ((const float*)p)[i];
}
__device__ __forceinline__ float gelu_f(float x){ return 0.5f*x*(1.0f+erff(x*0.7071067811865475f)); }

__device__ __forceinline__ uint4 load8bf(const void* p, size_t eoff, int isbf){
  if (isbf) return *(const uint4*)((const u16*)p + eoff);
  const float* f = (const float*)p + eoff;
  uint4 r;
  r.x = (unsigned)f2bf(f[0]) | ((unsigned)f2bf(f[1])<<16);
  r.y = (unsigned)f2bf(f[2]) | ((unsigned)f2bf(f[3])<<16);
  r.z = (unsigned)f2bf(f[4]) | ((unsigned)f2bf(f[5])<<16);
  r.w = (unsigned)f2bf(f[6]) | ((unsigned)f2bf(f[7])<<16);
  return r;
}
__device__ __forceinline__ uint2 load4bf(const void* p, size_t eoff, int isbf){
  if (isbf) return *(const uint2*)((const u16*)p + eoff);
  const float* f = (const float*)p + eoff;
  uint2 r;
  r.x = (unsigned)f2bf(f[0]) | ((unsigned)f2bf(f[1])<<16);
  r.y = (unsigned)f2bf(f[2]) | ((unsigned)f2bf(f[3])<<16);
  return r;
}

// ---------------- dtype detector ----------------
__global__ void k_detect(const void* nf, int* flag)
{
  int t = threadIdx.x;
  const float* f = (const float*)nf;
  int cnt = 0;
  for (int i = t; i < 4096; i += 256) {
    float a = fabsf(f[i]);
    if (a > 1e-5f && a < 100.0f) cnt++;   // NaN compares false
  }
  __shared__ int s[256];
  s[t] = cnt; __syncthreads();
  for (int st = 128; st > 0; st >>= 1) { if (t < st) s[t] += s[t+st]; __syncthreads(); }
  if (t == 0) *flag = (s[0] < 2048) ? 1 : 0;
}

// ---------------- MFMA GEMM 64x64 tiles: C[M,N] = A[M,K] @ B[N,K]^T (+bias)(+gelu) ----------------
// a_fmt: 0 fp32 internal, 1 bf16 internal, 2 external (detected). 4 waves, each 32x32 (2x2 MFMA tiles).
template<int ACT, int CFMT>
__global__ __launch_bounds__(256)
void mfma_gemm(const void* __restrict__ A, int a_fmt,
               const void* __restrict__ B, size_t boff,
               const void* __restrict__ bias, size_t bioff, int has_bias,
               void* __restrict__ C, int M, int N, int K,
               const int* __restrict__ dflag)
{
  int isbf = *dflag;
  int af = (a_fmt == 2) ? isbf : a_fmt;
  __shared__ u16 As[64*40];
  __shared__ u16 Bs[64*40];
  int bm = blockIdx.y*64, bn = blockIdx.x*64;
  int t = threadIdx.x;
  int w = t>>6, lane = t&63, l4 = lane&15, quad = lane>>4;
  int wm = w>>1, wn = w&1;
  f4v zero = {0.f,0.f,0.f,0.f};
  f4v acc[2][2];
  acc[0][0]=zero; acc[0][1]=zero; acc[1][0]=zero; acc[1][1]=zero;

  for (int k0 = 0; k0 < K; k0 += 32) {
    __syncthreads();
    {
      int row = t>>2, sk = t&3;
      *(uint4*)&As[row*40 + sk*8] = load8bf(A, (size_t)(bm+row)*K + k0 + sk*8, af);
      *(uint4*)&Bs[row*40 + sk*8] = load8bf(B, boff + (size_t)(bn+row)*K + k0 + sk*8, isbf);
    }
    __syncthreads();
    s8v a[2], b[2];
    #pragma unroll
    for (int i=0;i<2;i++) a[i] = *(const s8v*)&As[(wm*32 + i*16 + l4)*40 + quad*8];
    #pragma unroll
    for (int j=0;j<2;j++) b[j] = *(const s8v*)&Bs[(wn*32 + j*16 + l4)*40 + quad*8];
    #pragma unroll
    for (int i=0;i<2;i++)
      #pragma unroll
      for (int j=0;j<2;j++)
        acc[i][j] = __builtin_amdgcn_mfma_f32_16x16x32_bf16(a[i], b[j], acc[i][j], 0,0,0);
  }
  #pragma unroll
  for (int i=0;i<2;i++)
    #pragma unroll
    for (int j=0;j<2;j++) {
      int col = bn + wn*32 + j*16 + l4;
      float bv = has_bias ? ldf(bias, bioff + col, isbf) : 0.f;
      #pragma unroll
      for (int r=0;r<4;r++) {
        int row = bm + wm*32 + i*16 + quad*4 + r;
        float v = acc[i][j][r] + bv;
        if (ACT==1) v = gelu_f(v);
        if (CFMT==1) ((u16*)C)[(size_t)row*N + col] = f2bf(v);
        else         ((float*)C)[(size_t)row*N + col] = v;
      }
    }
}

// ---------------- CSR build ----------------
__global__ void k_count(const int* __restrict__ dst, int* __restrict__ deg)
{
  int e = blockIdx.x*256 + threadIdx.x;
  if (e >= ET) return;
  int d = (e < EE) ? dst[e] : (e - EE);
  atomicAdd(&deg[d], 1);
}

__global__ void k_scan(const int* __restrict__ deg, int* __restrict__ rowstart)
{
  __shared__ int csum[256];
  int t = threadIdx.x;
  int s = 0;
  for (int i=0;i<64;i++) s += deg[t*64+i];
  csum[t] = s;
  __syncthreads();
  if (t == 0) {
    int r = 0;
    for (int i=0;i<256;i++){ int v = csum[i]; csum[i] = r; r += v; }
    rowstart[NN] = r;
  }
  __syncthreads();
  int b = csum[t];
  for (int i=0;i<64;i++){ rowstart[t*64+i] = b; b += deg[t*64+i]; }
}

__global__ void k_scatter(const int* __restrict__ dst, const int* __restrict__ rowstart,
                          int* __restrict__ fill, int* __restrict__ csr)
{
  int e = blockIdx.x*256 + threadIdx.x;
  if (e >= ET) return;
  int d = (e < EE) ? dst[e] : (e - EE);
  int pos = rowstart[d] + atomicAdd(&fill[d], 1);
  csr[pos] = e;
}

__global__ void k_loopmean(const int* __restrict__ csr, const int* __restrict__ rowstart,
                           const void* __restrict__ edge_attr, u16* __restrict__ loopmean,
                           const int* __restrict__ dflag)
{
  int isbf = *dflag;
  int n = blockIdx.x, j = threadIdx.x;   // 64 threads
  int s = rowstart[n], e1 = rowstart[n+1];
  float sum = 0.f; int cnt = 0;
  for (int p = s; p < e1; ++p) {
    int eid = csr[p];
    if (eid < EE) { sum += ldf(edge_attr, (size_t)eid*64 + j, isbf); cnt++; }
  }
  loopmean[(size_t)n*64 + j] = f2bf(sum / (float)max(cnt, 1));
}

// Wc[l] = lin_edge_w[l] ([256,128]) @ init_edge_w ([128,64]) -> [L,256,64] bf16
__global__ void k_wc(const void* __restrict__ We, const void* __restrict__ iew,
                     u16* __restrict__ Wcb, const int* __restrict__ dflag)
{
  int isbf = *dflag;
  int idx = blockIdx.x*256 + threadIdx.x;    // 32768
  int j = idx & 63, c = (idx >> 6) & 255, l = idx >> 14;
  float s = 0.f;
  for (int k=0;k<128;k++) s += ldf(We, ((size_t)l*256 + c)*128 + k, isbf) * ldf(iew, (size_t)k*64 + j, isbf);
  Wcb[idx] = f2bf(s);
}

// ---------------- FUSED GAT: per node — e_emb (MFMA) + logits + online softmax + aggregate + LN1 ----------------
// Wave w owns channels [w*64, w*64+64) = heads 2w, 2w+1. Chunk = 16 edges; quad q owns edges q*4..q*4+3.
__global__ __launch_bounds__(256)
void k_gat(const int* __restrict__ csr, const int* __restrict__ rowstart, const int* __restrict__ src,
           const u16* __restrict__ Wcb, const u16* __restrict__ xl, const u16* __restrict__ xr,
           const float* __restrict__ xbuf,
           const void* __restrict__ edge_attr, const u16* __restrict__ loopmean,
           const void* __restrict__ att, size_t att_off,
           const void* __restrict__ gat_bias, const void* __restrict__ ln1g, const void* __restrict__ ln1b,
           size_t poff, float* __restrict__ hbuf, const int* __restrict__ dflag)
{
  int isbf = *dflag;
  __shared__ u16 Bs[256*72];      // Wc [c][k], stride 72
  __shared__ u16 sxl[16][264];    // gathered xl rows of the chunk's 16 edges
  __shared__ u16 sattr[16][72];   // chunk edge attrs (64 ch)
  __shared__ float sxr[256];
  __shared__ float satt[256];
  __shared__ float slog[16][8];
  __shared__ int ssrc[16], seid[16];
  __shared__ float rred[256];

  int t = threadIdx.x;
  int w = t>>6, lane = t&63, l4 = lane&15, quad = lane>>4;

  // stage Wc + att once per block
  #pragma unroll
  for (int it = 0; it < 8; ++it) {
    int sid = t + it*256;
    int row = sid >> 3, sk = sid & 7;
    *(uint4*)&Bs[row*72 + sk*8] = *(const uint4*)&Wcb[row*64 + sk*8];
  }
  satt[t] = ldf(att, att_off + t, isbf);

  for (int n = blockIdx.x; n < NN; n += gridDim.x) {
    int s = rowstart[n], deg = rowstart[n+1] - s;
    __syncthreads();                        // prev node done; Bs/satt visible on first iter
    sxr[t] = bfu(xr[(size_t)n*256 + t]);

    float m_run[2] = {-3.0e38f, -3.0e38f};  // heads 2w, 2w+1 (this quad's partial)
    float l_run[2] = {0.f, 0.f};
    float agg[4] = {0.f, 0.f, 0.f, 0.f};    // channels w*64 + jj*16 + l4

    for (int c0 = 0; c0 < deg; c0 += 16) {
      if (t < 16) {
        int eid = (c0 + t < deg) ? csr[s + c0 + t] : (EE + n);  // pad = self-loop (safe)
        seid[t] = eid;
        ssrc[t] = (eid < EE) ? src[eid] : (eid - EE);
      }
      __syncthreads();   // ids ready; prev chunk's sxl reads done
      {
        int e = t >> 4, g = t & 15;
        int eid = seid[e];
        uint2 v;
        if (eid < EE) v = load4bf(edge_attr, (size_t)eid*64 + g*4, isbf);
        else          v = *(const uint2*)&loopmean[(size_t)(eid-EE)*64 + g*4];
        *(uint2*)&sattr[e][g*4] = v;
      }
      #pragma unroll
      for (int it = 0; it < 2; ++it) {
        int idx = t + it*256;
        int e = idx >> 5, part = idx & 31;
        *(uint4*)&sxl[e][part*8] = *(const uint4*)&xl[(size_t)ssrc[e]*256 + part*8];
      }
      __syncthreads();   // staged

      // MFMA: ge[edge 0..15][c = w*64+jj*16+l4]
      s8v a0 = *(const s8v*)&sattr[l4][quad*8];
      s8v a1 = *(const s8v*)&sattr[l4][32 + quad*8];
      f4v zero = {0.f,0.f,0.f,0.f};
      f4v acc[4];
      #pragma unroll
      for (int jj=0;jj<4;jj++){
        int c = w*64 + jj*16 + l4;
        s8v b0 = *(const s8v*)&Bs[c*72 + quad*8];
        s8v b1 = *(const s8v*)&Bs[c*72 + 32 + quad*8];
        acc[jj] = __builtin_amdgcn_mfma_f32_16x16x32_bf16(a0, b0, zero, 0,0,0);
        acc[jj] = __builtin_amdgcn_mfma_f32_16x16x32_bf16(a1, b1, acc[jj], 0,0,0);
      }
      // logits for this quad's 4 edge-rows
      #pragma unroll
      for (int r=0;r<4;++r){
        int e = quad*4 + r;
        float p0 = 0.f, p1 = 0.f;
        #pragma unroll
        for (int jj=0;jj<4;jj++){
          int c = w*64 + jj*16 + l4;
          float m = acc[jj][r] + bfu(sxl[e][c]) + sxr[c];
          float g = (m >= 0.f) ? m : 0.2f*m;
          float v = satt[c]*g;
          if (jj < 2) p0 += v; else p1 += v;
        }
        p0 += __shfl_xor(p0,1); p0 += __shfl_xor(p0,2); p0 += __shfl_xor(p0,4); p0 += __shfl_xor(p0,8);
        p1 += __shfl_xor(p1,1); p1 += __shfl_xor(p1,2); p1 += __shfl_xor(p1,4); p1 += __shfl_xor(p1,8);
        if (l4 == 0 && (c0 + e) < deg) { slog[e][w*2] = p0; slog[e][w*2+1] = p1; }
      }
      __syncthreads();   // slog ready

      // online softmax update: quad handles its own 4 edges
      #pragma unroll
      for (int r=0;r<4;++r){
        int e = quad*4 + r;
        if (c0 + e < deg) {
          float lg0 = slog[e][w*2], lg1 = slog[e][w*2+1];
          float mn0 = fmaxf(m_run[0], lg0), mn1 = fmaxf(m_run[1], lg1);
          float sc0 = __expf(m_run[0]-mn0), sc1 = __expf(m_run[1]-mn1);
          float w0  = __expf(lg0-mn0),      w1  = __expf(lg1-mn1);
          m_run[0] = mn0; m_run[1] = mn1;
          l_run[0] = l_run[0]*sc0 + w0;
          l_run[1] = l_run[1]*sc1 + w1;
          agg[0] = agg[0]*sc0 + w0*bfu(sxl[e][w*64      + l4]);
          agg[1] = agg[1]*sc0 + w0*bfu(sxl[e][w*64 + 16 + l4]);
          agg[2] = agg[2]*sc1 + w1*bfu(sxl[e][w*64 + 32 + l4]);
          agg[3] = agg[3]*sc1 + w1*bfu(sxl[e][w*64 + 48 + l4]);
        }
      }
    }

    // merge across quads (butterfly over lane xor 16, 32)
    #pragma unroll
    for (int step = 16; step <= 32; step <<= 1) {
      #pragma unroll
      for (int k2 = 0; k2 < 2; ++k2) {
        float mo = __shfl_xor(m_run[k2], step);
        float lo = __shfl_xor(l_run[k2], step);
        float a0 = __shfl_xor(agg[2*k2],   step);
        float a1 = __shfl_xor(agg[2*k2+1], step);
        float mn = fmaxf(m_run[k2], mo);
        float sa = __expf(m_run[k2]-mn), sb = __expf(mo-mn);
        l_run[k2]  = l_run[k2]*sa + lo*sb;
        agg[2*k2]   = agg[2*k2]*sa   + a0*sb;
        agg[2*k2+1] = agg[2*k2+1]*sa + a1*sb;
        m_run[k2] = mn;
      }
    }

    // thread t keeps channel t = w*64 + quad*16 + l4  (jj == quad)
    float myout = agg[quad] / (l_run[quad>>1] + 1e-16f)
                + ldf(gat_bias, poff + t, isbf) + xbuf[(size_t)n*256 + t];

    // LN1
    rred[t] = myout; __syncthreads();
    for (int st = 128; st > 0; st >>= 1) { if (t < st) rred[t] += rred[t+st]; __syncthreads(); }
    float mu = rred[0] * (1.f/256.f);
    __syncthreads();
    float d = myout - mu;
    rred[t] = d*d; __syncthreads();
    for (int st = 128; st > 0; st >>= 1) { if (t < st) rred[t] += rred[t+st]; __syncthreads(); }
    float var = rred[0] * (1.f/256.f);
    hbuf[(size_t)n*256 + t] = d * rsqrtf(var + 1e-5f) * ldf(ln1g, poff + t, isbf) + ldf(ln1b, poff + t, isbf);
  }
}

// ---------------- residual + LN2 -> xbuf ----------------
__global__ __launch_bounds__(256)
void k_ln_add(const float* __restrict__ a, const u16* __restrict__ b2,
              const void* __restrict__ gg, const void* __restrict__ bb, size_t poff,
              float* __restrict__ out, const int* __restrict__ dflag)
{
  int isbf = *dflag;
  int n = blockIdx.x, t = threadIdx.x;
  __shared__ float r[256];
  float x = a[(size_t)n*256 + t] + bfu(b2[(size_t)n*256 + t]);
  r[t] = x; __syncthreads();
  for (int st = 128; st > 0; st >>= 1) { if (t < st) r[t] += r[t+st]; __syncthreads(); }
  float mu = r[0] * (1.f/256.f);
  __syncthreads();
  float d = x - mu;
  r[t] = d*d; __syncthreads();
  for (int st = 128; st > 0; st >>= 1) { if (t < st) r[t] += r[t+st]; __syncthreads(); }
  float var = r[0] * (1.f/256.f);
  out[(size_t)n*256 + t] = d * rsqrtf(var + 1e-5f) * ldf(gg, poff + t, isbf) + ldf(bb, poff + t, isbf);
}

__global__ void k_out(const float* __restrict__ x, void* __restrict__ out, const int* __restrict__ dflag)
{
  int isbf = *dflag;
  int i = blockIdx.x*256 + threadIdx.x;
  if (isbf) ((u16*)out)[i] = f2bf(x[i]);
  else      ((float*)out)[i] = x[i];
}

extern "C" void kernel_launch(void* const* d_in, const int* in_sizes, int n_in,
                              void* d_out, int out_size, void* d_ws, size_t ws_size,
                              hipStream_t stream)
{
  const void* node_feats = d_in[0];
  const int*  edge_index = (const int*)d_in[1];
  const void* edge_attr  = d_in[2];
  const void* init_node_w= d_in[3];
  const void* init_edge_w= d_in[4];
  const void* lin_l_w    = d_in[5];
  const void* lin_l_b    = d_in[6];
  const void* lin_r_w    = d_in[7];
  const void* lin_r_b    = d_in[8];
  const void* lin_edge_w = d_in[9];
  const void* att        = d_in[10];
  const void* gat_bias   = d_in[11];
  const void* ln1_g      = d_in[12];
  const void* ln1_b      = d_in[13];
  const void* mlp_w1     = d_in[14];
  const void* mlp_w2     = d_in[15];
  const void* ln2_g      = d_in[16];
  const void* ln2_b      = d_in[17];

  const int* srcp = edge_index;
  const int* dstp = edge_index + EE;

  char* p = (char*)d_ws;
  auto alloc = [&](size_t bytes) { void* r = (void*)p; p += (bytes + 255) & ~(size_t)255; return r; };
  int*   dflag   = (int*)alloc(256);
  int*   deg     = (int*)alloc((size_t)NN*4);
  int*   rowstart= (int*)alloc((size_t)(NN+1)*4);
  int*   fill    = (int*)alloc((size_t)NN*4);
  int*   csr     = (int*)alloc((size_t)ET*4);
  u16*   Wcb     = (u16*)alloc((size_t)2*256*64*2);
  u16*   loopmean= (u16*)alloc((size_t)NN*64*2);
  float* xbuf    = (float*)alloc((size_t)NN*256*4);
  float* hbuf    = (float*)alloc((size_t)NN*256*4);
  u16*   xl      = (u16*)alloc((size_t)NN*256*2);
  u16*   xr      = (u16*)alloc((size_t)NN*256*2);
  u16*   ymid    = xl;              // [NN,512] bf16 aliases xl+xr (dead at MLP time)
  u16*   y2      = (u16*)d_out;     // bf16 scratch; final k_out overwrites

  hipMemsetAsync(deg,  0, (size_t)NN*4, stream);
  hipMemsetAsync(fill, 0, (size_t)NN*4, stream);

  k_detect <<<1, 256, 0, stream>>>(node_feats, dflag);

  k_count  <<<(ET+255)/256, 256, 0, stream>>>(dstp, deg);
  k_scan   <<<1, 256, 0, stream>>>(deg, rowstart);
  k_scatter<<<(ET+255)/256, 256, 0, stream>>>(dstp, rowstart, fill, csr);
  k_loopmean<<<NN, 64, 0, stream>>>(csr, rowstart, edge_attr, loopmean, dflag);
  k_wc     <<<128, 256, 0, stream>>>(lin_edge_w, init_edge_w, Wcb, dflag);

  // x = node_feats @ init_node_w.T  (fp32 out)
  mfma_gemm<0,0><<<dim3(4,256), 256, 0, stream>>>(node_feats, 2, init_node_w, 0, nullptr, 0, 0,
                                                  xbuf, NN, 256, 768, dflag);

  for (int l = 0; l < 2; ++l) {
    size_t wo = (size_t)l*256*256;
    size_t bo = (size_t)l*256;
    mfma_gemm<0,1><<<dim3(4,256), 256, 0, stream>>>(xbuf, 0, lin_l_w, wo, lin_l_b, bo, 1,
                                                    xl, NN, 256, 256, dflag);
    mfma_gemm<0,1><<<dim3(4,256), 256, 0, stream>>>(xbuf, 0, lin_r_w, wo, lin_r_b, bo, 1,
                                                    xr, NN, 256, 256, dflag);
    k_gat<<<768, 256, 0, stream>>>(csr, rowstart, srcp, Wcb + (size_t)l*256*64, xl, xr, xbuf,
                                   edge_attr, loopmean, att, (size_t)l*256,
                                   gat_bias, ln1_g, ln1_b, bo, hbuf, dflag);
    mfma_gemm<1,1><<<dim3(8,256), 256, 0, stream>>>(hbuf, 0, mlp_w1, (size_t)l*512*256, nullptr, 0, 0,
                                                    ymid, NN, 512, 256, dflag);
    mfma_gemm<0,1><<<dim3(4,256), 256, 0, stream>>>(ymid, 1, mlp_w2, (size_t)l*256*512, nullptr, 0, 0,
                                                    y2, NN, 256, 512, dflag);
    k_ln_add<<<NN, 256, 0, stream>>>(hbuf, y2, ln2_g, ln2_b, bo, xbuf, dflag);
  }

  k_out<<<(NN*256)/256, 256, 0, stream>>>(xbuf, d_out, dflag);
}

// Round 6
// 778.685 us; speedup vs baseline: 3.8296x; 1.1456x over previous
//
#include <hip/hip_runtime.h>

typedef unsigned short u16;
typedef __attribute__((ext_vector_type(8))) short s8v;   // 8 bf16 (4 VGPRs) — MFMA A/B frag
typedef __attribute__((ext_vector_type(4))) float f4v;   // 4 fp32 — MFMA C/D frag

#define NN 16384
#define EE 262144
#define ET (EE + NN)      // 278528 = 4352 * 64
#define NTILES (ET / 64)  // 4352

__device__ __forceinline__ float bfu(u16 h){ return __uint_as_float((unsigned)h << 16); }
__device__ __forceinline__ u16 f2bf(float f){
  unsigned u = __float_as_uint(f);
  unsigned r = u + 0x7FFFu + ((u >> 16) & 1u);   // RNE
  return (u16)(r >> 16);
}
__device__ __forceinline__ float ldf(const void* p, size_t i, int isbf){
  return isbf ? bfu(((const u16*)p)[i]) : ((const float*)p)[i];
}
__device__ __forceinline__ float gelu_f(float x){ return 0.5f*x*(1.0f+erff(x*0.7071067811865475f)); }

__device__ __forceinline__ uint4 load8bf(const void* p, size_t eoff, int isbf){
  if (isbf) return *(const uint4*)((const u16*)p + eoff);
  const float* f = (const float*)p + eoff;
  uint4 r;
  r.x = (unsigned)f2bf(f[0]) | ((unsigned)f2bf(f[1])<<16);
  r.y = (unsigned)f2bf(f[2]) | ((unsigned)f2bf(f[3])<<16);
  r.z = (unsigned)f2bf(f[4]) | ((unsigned)f2bf(f[5])<<16);
  r.w = (unsigned)f2bf(f[6]) | ((unsigned)f2bf(f[7])<<16);
  return r;
}

// ---------------- dtype detector ----------------
__global__ void k_detect(const void* nf, int* flag)
{
  int t = threadIdx.x;
  const float* f = (const float*)nf;
  int cnt = 0;
  for (int i = t; i < 4096; i += 256) {
    float a = fabsf(f[i]);
    if (a > 1e-5f && a < 100.0f) cnt++;   // NaN compares false
  }
  __shared__ int s[256];
  s[t] = cnt; __syncthreads();
  for (int st = 128; st > 0; st >>= 1) { if (t < st) s[t] += s[t+st]; __syncthreads(); }
  if (t == 0) *flag = (s[0] < 2048) ? 1 : 0;
}

// ---------------- MFMA GEMM 128x128 tiles: C[M,N] = A @ B^T (+bias)(+gelu), dual-B split ----------------
// a_fmt: 0 fp32 internal, 1 bf16 internal, 2 external (detected).
template<int ACT, int CFMT>
__global__ __launch_bounds__(256)
void mfma_gemm(const void* __restrict__ A, int a_fmt,
               const void* __restrict__ B1, size_t b1off,
               const void* __restrict__ B2, size_t b2off, int nsplit,
               const void* __restrict__ bias1, const void* __restrict__ bias2,
               size_t bioff, int has_bias,
               void* __restrict__ C, int M, int N, int K,
               const int* __restrict__ dflag)
{
  int isbf = *dflag;
  int af = (a_fmt == 2) ? isbf : a_fmt;
  __shared__ u16 As[128*40];
  __shared__ u16 Bs[128*40];
  int bm = blockIdx.y*128, bn = blockIdx.x*128;
  int t = threadIdx.x;
  int w = t>>6, lane = t&63, l4 = lane&15, quad = lane>>4;
  int wm = w>>1, wn = w&1;
  f4v zero = {0.f,0.f,0.f,0.f};
  f4v acc[4][4];
  #pragma unroll
  for (int i=0;i<4;i++)
    #pragma unroll
    for (int j=0;j<4;j++) acc[i][j] = zero;

  for (int k0 = 0; k0 < K; k0 += 32) {
    __syncthreads();
    #pragma unroll
    for (int it = 0; it < 2; ++it) {
      int sid = t + it*256;
      int row = sid >> 2, sk = sid & 3;
      *(uint4*)&As[row*40 + sk*8] = load8bf(A, (size_t)(bm+row)*K + k0 + sk*8, af);
      int col = bn + row;
      uint4 vb;
      if (col < nsplit) vb = load8bf(B1, b1off + (size_t)col*K + k0 + sk*8, isbf);
      else              vb = load8bf(B2, b2off + (size_t)(col-nsplit)*K + k0 + sk*8, isbf);
      *(uint4*)&Bs[row*40 + sk*8] = vb;
    }
    __syncthreads();
    s8v a[4], b[4];
    #pragma unroll
    for (int i=0;i<4;i++) a[i] = *(const s8v*)&As[(wm*64 + i*16 + l4)*40 + quad*8];
    #pragma unroll
    for (int j=0;j<4;j++) b[j] = *(const s8v*)&Bs[(wn*64 + j*16 + l4)*40 + quad*8];
    #pragma unroll
    for (int i=0;i<4;i++)
      #pragma unroll
      for (int j=0;j<4;j++)
        acc[i][j] = __builtin_amdgcn_mfma_f32_16x16x32_bf16(a[i], b[j], acc[i][j], 0,0,0);
  }
  #pragma unroll
  for (int i=0;i<4;i++)
    #pragma unroll
    for (int j=0;j<4;j++) {
      int col = bn + wn*64 + j*16 + l4;
      float bv = 0.f;
      if (has_bias) bv = (col < nsplit) ? ldf(bias1, bioff + col, isbf)
                                        : ldf(bias2, bioff + col - nsplit, isbf);
      #pragma unroll
      for (int r=0;r<4;r++) {
        int row = bm + wm*64 + i*16 + quad*4 + r;
        float v = acc[i][j][r] + bv;
        if (ACT==1) v = gelu_f(v);
        if (CFMT==1) ((u16*)C)[(size_t)row*N + col] = f2bf(v);
        else         ((float*)C)[(size_t)row*N + col] = v;
      }
    }
}

// ---------------- CSR build ----------------
__global__ void k_count(const int* __restrict__ dst, int* __restrict__ deg)
{
  int e = blockIdx.x*256 + threadIdx.x;
  if (e >= ET) return;
  int d = (e < EE) ? dst[e] : (e - EE);
  atomicAdd(&deg[d], 1);
}

__global__ void k_scan(const int* __restrict__ deg, int* __restrict__ rowstart)
{
  __shared__ int csum[256];
  int t = threadIdx.x;
  int s = 0;
  for (int i=0;i<64;i++) s += deg[t*64+i];
  csum[t] = s;
  __syncthreads();
  if (t == 0) {
    int r = 0;
    for (int i=0;i<256;i++){ int v = csum[i]; csum[i] = r; r += v; }
    rowstart[NN] = r;
  }
  __syncthreads();
  int b = csum[t];
  for (int i=0;i<64;i++){ rowstart[t*64+i] = b; b += deg[t*64+i]; }
}

__global__ void k_scatter(const int* __restrict__ dst, const int* __restrict__ rowstart,
                          int* __restrict__ fill, int* __restrict__ csr)
{
  int e = blockIdx.x*256 + threadIdx.x;
  if (e >= ET) return;
  int d = (e < EE) ? dst[e] : (e - EE);
  int pos = rowstart[d] + atomicAdd(&fill[d], 1);
  csr[pos] = e;
}

__global__ void k_loopmean(const int* __restrict__ csr, const int* __restrict__ rowstart,
                           const void* __restrict__ edge_attr, u16* __restrict__ loopmean,
                           const int* __restrict__ dflag)
{
  int isbf = *dflag;
  int n = blockIdx.x, j = threadIdx.x;   // 64 threads
  int s = rowstart[n], e1 = rowstart[n+1];
  float sum = 0.f; int cnt = 0;
  for (int p = s; p < e1; ++p) {
    int eid = csr[p];
    if (eid < EE) { sum += ldf(edge_attr, (size_t)eid*64 + j, isbf); cnt++; }
  }
  loopmean[(size_t)n*64 + j] = f2bf(sum / (float)max(cnt, 1));
}

// Wc[l] = lin_edge_w[l] ([256,128]) @ init_edge_w ([128,64]) -> [L,256,64] bf16
__global__ void k_wc(const void* __restrict__ We, const void* __restrict__ iew,
                     u16* __restrict__ Wcb, const int* __restrict__ dflag)
{
  int isbf = *dflag;
  int idx = blockIdx.x*256 + threadIdx.x;    // 32768
  int j = idx & 63, c = (idx >> 6) & 255, l = idx >> 14;
  float s = 0.f;
  for (int k=0;k<128;k++) s += ldf(We, ((size_t)l*256 + c)*128 + k, isbf) * ldf(iew, (size_t)k*64 + j, isbf);
  Wcb[idx] = f2bf(s);
}

// ---------------- edge-parallel logits (geT MFMA layout: lane l4 = edge) ----------------
__global__ __launch_bounds__(256)
void k_elogits(const int* __restrict__ src, const int* __restrict__ dst,
               const u16* __restrict__ Wcb, const u16* __restrict__ xlr,
               const void* __restrict__ edge_attr, const u16* __restrict__ loopmean,
               const void* __restrict__ att, size_t att_off,
               float* __restrict__ logits, const int* __restrict__ dflag)
{
  int isbf = *dflag;
  __shared__ u16 WcF[32*64*8];    // 32 A-frags x 64 lanes x 8 bf16 (frag-order, conflict-free b128)
  __shared__ u16 attr_s[64*72];   // 64 edges x 64ch, stride 72
  __shared__ float satt[256];
  __shared__ int ssrc[64], sdst[64];

  int t = threadIdx.x;
  int w = t>>6, lane = t&63, l4 = lane&15, quad = lane>>4;

  // one-time: att + Wc fragments (A-frag for m-tile i, k-step ks is identical for all waves)
  satt[t] = ldf(att, att_off + t, isbf);
  #pragma unroll
  for (int f = 0; f < 8; ++f) {
    int fr = w + f*4;              // 0..31
    int i = fr >> 1, ks = fr & 1;
    *(uint4*)&WcF[(fr*64 + lane)*8] = *(const uint4*)&Wcb[(size_t)(16*i + l4)*64 + ks*32 + quad*8];
  }

  f4v zero = {0.f,0.f,0.f,0.f};
  for (int tile = blockIdx.x; tile < NTILES; tile += gridDim.x) {
    int e0 = tile*64;
    __syncthreads();               // attr_s/ssrc reuse safe; first iter: WcF/satt visible after this
    if (t < 64) {
      int e = e0 + t;
      ssrc[t] = (e < EE) ? src[e] : (e - EE);
      sdst[t] = (e < EE) ? dst[e] : (e - EE);
    }
    {
      int er = t >> 2, part = t & 3;
      int e = e0 + er;
      uint4 v0, v1;
      if (e < EE) {
        v0 = load8bf(edge_attr, (size_t)e*64 + part*16,     isbf);
        v1 = load8bf(edge_attr, (size_t)e*64 + part*16 + 8, isbf);
      } else {
        v0 = *(const uint4*)&loopmean[(size_t)(e-EE)*64 + part*16];
        v1 = *(const uint4*)&loopmean[(size_t)(e-EE)*64 + part*16 + 8];
      }
      *(uint4*)&attr_s[er*72 + part*16]     = v0;
      *(uint4*)&attr_s[er*72 + part*16 + 8] = v1;
    }
    __syncthreads();

    // MFMA: D[ch 256][edge 16 per wave]; b-frag rows = this wave's 16 edges
    s8v b0 = *(const s8v*)&attr_s[(w*16 + l4)*72 + quad*8];
    s8v b1 = *(const s8v*)&attr_s[(w*16 + l4)*72 + 32 + quad*8];
    f4v acc[16];
    #pragma unroll
    for (int i=0;i<16;++i){
      s8v a0 = *(const s8v*)&WcF[((2*i  )*64 + lane)*8];
      s8v a1 = *(const s8v*)&WcF[((2*i+1)*64 + lane)*8];
      acc[i] = __builtin_amdgcn_mfma_f32_16x16x32_bf16(a0, b0, zero, 0,0,0);
      acc[i] = __builtin_amdgcn_mfma_f32_16x16x32_bf16(a1, b1, acc[i], 0,0,0);
    }

    // epilogue: lane's edge = e0 + w*16 + l4; its channels = {16i + quad*4 + r}
    int me = w*16 + l4;
    int sn = ssrc[me], dn = sdst[me];
    float ph[8] = {0.f,0.f,0.f,0.f,0.f,0.f,0.f,0.f};
    #pragma unroll
    for (int i=0;i<16;++i){
      uint2 xlv = *(const uint2*)&xlr[(size_t)sn*512 +       i*16 + quad*4];
      uint2 xrv = *(const uint2*)&xlr[(size_t)dn*512 + 256 + i*16 + quad*4];
      float4 av = *(const float4*)&satt[i*16 + quad*4];
      float m0 = acc[i][0] + bfu((u16)(xlv.x & 0xffff)) + bfu((u16)(xrv.x & 0xffff));
      float m1 = acc[i][1] + bfu((u16)(xlv.x >> 16))    + bfu((u16)(xrv.x >> 16));
      float m2 = acc[i][2] + bfu((u16)(xlv.y & 0xffff)) + bfu((u16)(xrv.y & 0xffff));
      float m3 = acc[i][3] + bfu((u16)(xlv.y >> 16))    + bfu((u16)(xrv.y >> 16));
      float g0 = fmaxf(m0, 0.2f*m0), g1 = fmaxf(m1, 0.2f*m1);
      float g2 = fmaxf(m2, 0.2f*m2), g3 = fmaxf(m3, 0.2f*m3);
      ph[i>>1] += av.x*g0 + av.y*g1 + av.z*g2 + av.w*g3;
    }
    #pragma unroll
    for (int h=0;h<8;++h){
      ph[h] += __shfl_xor(ph[h], 16);
      ph[h] += __shfl_xor(ph[h], 32);
    }
    if (quad == 0){
      float4 lo = {ph[0], ph[1], ph[2], ph[3]};
      float4 hi = {ph[4], ph[5], ph[6], ph[7]};
      *(float4*)&logits[(size_t)(e0 + me)*8]     = lo;
      *(float4*)&logits[(size_t)(e0 + me)*8 + 4] = hi;
    }
  }
}

// ---------------- one wave per node: online softmax + aggregate + bias + residual + LN1 ----------------
__global__ __launch_bounds__(256)
void k_aggln(const int* __restrict__ csr, const int* __restrict__ rowstart, const int* __restrict__ src,
             const float* __restrict__ logits, const u16* __restrict__ xlr, const float* __restrict__ xbuf,
             const void* __restrict__ gat_bias, const void* __restrict__ ln1g, const void* __restrict__ ln1b,
             size_t poff, float* __restrict__ hbuf, const int* __restrict__ dflag)
{
  int isbf = *dflag;
  int lane = threadIdx.x & 63, wid = threadIdx.x >> 6;
  int n = blockIdx.x*4 + wid;
  int s = rowstart[n], deg = rowstart[n+1] - s;
  int myh = lane >> 3;                       // head of channels 4*lane..4*lane+3
  float mrun = -3.0e38f, lrun = 0.f;
  float a0=0.f, a1=0.f, a2=0.f, a3=0.f;

  for (int c0 = 0; c0 < deg; c0 += 64) {
    int idx = s + c0 + lane; if (idx >= ET) idx = ET-1;
    int ev = csr[idx];
    int sv = (ev < EE) ? src[ev] : (ev - EE);
    int lim = min(64, deg - c0);
    for (int j = 0; j < lim; ++j) {
      int eid = __shfl(ev, j);
      int sn  = __shfl(sv, j);
      float lg = logits[(size_t)eid*8 + myh];
      uint2 xv = *(const uint2*)&xlr[(size_t)sn*512 + 4*lane];
      float mn = fmaxf(mrun, lg);
      float sc = __expf(mrun - mn);
      float wv = __expf(lg - mn);
      mrun = mn;
      lrun = lrun*sc + wv;
      a0 = a0*sc + wv*bfu((u16)(xv.x & 0xffff));
      a1 = a1*sc + wv*bfu((u16)(xv.x >> 16));
      a2 = a2*sc + wv*bfu((u16)(xv.y & 0xffff));
      a3 = a3*sc + wv*bfu((u16)(xv.y >> 16));
    }
  }
  float inv = 1.f/(lrun + 1e-16f);
  int c = 4*lane;
  float4 res = *(const float4*)&xbuf[(size_t)n*256 + c];
  float o0 = a0*inv + ldf(gat_bias, poff+c+0, isbf) + res.x;
  float o1 = a1*inv + ldf(gat_bias, poff+c+1, isbf) + res.y;
  float o2 = a2*inv + ldf(gat_bias, poff+c+2, isbf) + res.z;
  float o3 = a3*inv + ldf(gat_bias, poff+c+3, isbf) + res.w;

  float v = o0+o1+o2+o3;
  #pragma unroll
  for (int off=1; off<64; off<<=1) v += __shfl_xor(v, off);
  float mu = v * (1.f/256.f);
  float d0=o0-mu, d1=o1-mu, d2=o2-mu, d3=o3-mu;
  float v2 = d0*d0+d1*d1+d2*d2+d3*d3;
  #pragma unroll
  for (int off=1; off<64; off<<=1) v2 += __shfl_xor(v2, off);
  float wn = rsqrtf(v2*(1.f/256.f) + 1e-5f);
  float4 outv;
  outv.x = d0*wn*ldf(ln1g, poff+c+0, isbf) + ldf(ln1b, poff+c+0, isbf);
  outv.y = d1*wn*ldf(ln1g, poff+c+1, isbf) + ldf(ln1b, poff+c+1, isbf);
  outv.z = d2*wn*ldf(ln1g, poff+c+2, isbf) + ldf(ln1b, poff+c+2, isbf);
  outv.w = d3*wn*ldf(ln1g, poff+c+3, isbf) + ldf(ln1b, poff+c+3, isbf);
  *(float4*)&hbuf[(size_t)n*256 + c] = outv;
}

// ---------------- residual + LN2 -> xbuf ----------------
__global__ __launch_bounds__(256)
void k_ln_add(const float* __restrict__ a, const u16* __restrict__ b2,
              const void* __restrict__ gg, const void* __restrict__ bb, size_t poff,
              float* __restrict__ out, const int* __restrict__ dflag)
{
  int isbf = *dflag;
  int n = blockIdx.x, t = threadIdx.x;
  __shared__ float r[256];
  float x = a[(size_t)n*256 + t] + bfu(b2[(size_t)n*256 + t]);
  r[t] = x; __syncthreads();
  for (int st = 128; st > 0; st >>= 1) { if (t < st) r[t] += r[t+st]; __syncthreads(); }
  float mu = r[0] * (1.f/256.f);
  __syncthreads();
  float d = x - mu;
  r[t] = d*d; __syncthreads();
  for (int st = 128; st > 0; st >>= 1) { if (t < st) r[t] += r[t+st]; __syncthreads(); }
  float var = r[0] * (1.f/256.f);
  out[(size_t)n*256 + t] = d * rsqrtf(var + 1e-5f) * ldf(gg, poff + t, isbf) + ldf(bb, poff + t, isbf);
}

__global__ void k_out(const float* __restrict__ x, void* __restrict__ out, const int* __restrict__ dflag)
{
  int isbf = *dflag;
  int i = blockIdx.x*256 + threadIdx.x;
  if (isbf) ((u16*)out)[i] = f2bf(x[i]);
  else      ((float*)out)[i] = x[i];
}

extern "C" void kernel_launch(void* const* d_in, const int* in_sizes, int n_in,
                              void* d_out, int out_size, void* d_ws, size_t ws_size,
                              hipStream_t stream)
{
  const void* node_feats = d_in[0];
  const int*  edge_index = (const int*)d_in[1];
  const void* edge_attr  = d_in[2];
  const void* init_node_w= d_in[3];
  const void* init_edge_w= d_in[4];
  const void* lin_l_w    = d_in[5];
  const void* lin_l_b    = d_in[6];
  const void* lin_r_w    = d_in[7];
  const void* lin_r_b    = d_in[8];
  const void* lin_edge_w = d_in[9];
  const void* att        = d_in[10];
  const void* gat_bias   = d_in[11];
  const void* ln1_g      = d_in[12];
  const void* ln1_b      = d_in[13];
  const void* mlp_w1     = d_in[14];
  const void* mlp_w2     = d_in[15];
  const void* ln2_g      = d_in[16];
  const void* ln2_b      = d_in[17];

  const int* srcp = edge_index;
  const int* dstp = edge_index + EE;

  char* p = (char*)d_ws;
  auto alloc = [&](size_t bytes) { void* r = (void*)p; p += (bytes + 255) & ~(size_t)255; return r; };
  int*   dflag   = (int*)alloc(256);
  int*   deg     = (int*)alloc((size_t)NN*4);
  int*   rowstart= (int*)alloc((size_t)(NN+1)*4);
  int*   fill    = (int*)alloc((size_t)NN*4);
  int*   csr     = (int*)alloc((size_t)ET*4);
  u16*   Wcb     = (u16*)alloc((size_t)2*256*64*2);
  u16*   loopmean= (u16*)alloc((size_t)NN*64*2);
  float* logits  = (float*)alloc((size_t)ET*8*4);
  float* xbuf    = (float*)alloc((size_t)NN*256*4);
  float* hbuf    = (float*)alloc((size_t)NN*256*4);
  u16*   xlr     = (u16*)alloc((size_t)NN*512*2);  // xl = cols 0..255, xr = cols 256..511
  u16*   ymid    = xlr;             // [NN,512] bf16 alias (xlr dead at MLP time)
  u16*   y2      = (u16*)d_out;     // bf16 scratch; final k_out overwrites

  hipMemsetAsync(deg,  0, (size_t)NN*4, stream);
  hipMemsetAsync(fill, 0, (size_t)NN*4, stream);

  k_detect <<<1, 256, 0, stream>>>(node_feats, dflag);

  k_count  <<<(ET+255)/256, 256, 0, stream>>>(dstp, deg);
  k_scan   <<<1, 256, 0, stream>>>(deg, rowstart);
  k_scatter<<<(ET+255)/256, 256, 0, stream>>>(dstp, rowstart, fill, csr);
  k_loopmean<<<NN, 64, 0, stream>>>(csr, rowstart, edge_attr, loopmean, dflag);
  k_wc     <<<128, 256, 0, stream>>>(lin_edge_w, init_edge_w, Wcb, dflag);

  // x = node_feats @ init_node_w.T  (fp32 out)
  mfma_gemm<0,0><<<dim3(2,128), 256, 0, stream>>>(node_feats, 2, init_node_w, 0, init_node_w, 0, 1<<29,
                                                  nullptr, nullptr, 0, 0, xbuf, NN, 256, 768, dflag);

  for (int l = 0; l < 2; ++l) {
    size_t wo = (size_t)l*256*256;
    size_t bo = (size_t)l*256;
    // xlr = [x@Wl^T + bl | x@Wr^T + br]  (dual-B, N=512)
    mfma_gemm<0,1><<<dim3(4,128), 256, 0, stream>>>(xbuf, 0, lin_l_w, wo, lin_r_w, wo, 256,
                                                    lin_l_b, lin_r_b, bo, 1, xlr, NN, 512, 256, dflag);
    k_elogits<<<768, 256, 0, stream>>>(srcp, dstp, Wcb + (size_t)l*256*64, xlr,
                                       edge_attr, loopmean, att, (size_t)l*256, logits, dflag);
    k_aggln<<<NN/4, 256, 0, stream>>>(csr, rowstart, srcp, logits, xlr, xbuf,
                                      gat_bias, ln1_g, ln1_b, bo, hbuf, dflag);
    mfma_gemm<1,1><<<dim3(4,128), 256, 0, stream>>>(hbuf, 0, mlp_w1, (size_t)l*512*256, mlp_w1, 0, 1<<29,
                                                    nullptr, nullptr, 0, 0, ymid, NN, 512, 256, dflag);
    mfma_gemm<0,1><<<dim3(2,128), 256, 0, stream>>>(ymid, 1, mlp_w2, (size_t)l*256*512, mlp_w2, 0, 1<<29,
                                                    nullptr, nullptr, 0, 0, y2, NN, 256, 512, dflag);
    k_ln_add<<<NN, 256, 0, stream>>>(hbuf, y2, ln2_g, ln2_b, bo, xbuf, dflag);
  }

  k_out<<<(NN*256)/256, 256, 0, stream>>>(xbuf, d_out, dflag);
}